// Round 2
// baseline (274.737 us; speedup 1.0000x reference)
//
#include <hip/hip_runtime.h>

#define Bb 128
#define Tt 1024
#define Ff 128
#define Kk 32

// ---------------------------------------------------------------------------
// Kernel 1: emission[b,t,k] = sum_f input[b,t,f] * W[f,k]
// grid 1024 x 256 threads; thread computes 4 rows x 4 k's; W staged in LDS.
// ---------------------------------------------------------------------------
__global__ __launch_bounds__(256) void emis_kernel(
    const float* __restrict__ inp, const float* __restrict__ W,
    float* __restrict__ em)
{
    __shared__ __align__(16) float Wl[Ff * Kk];   // 16 KB
    const int tid = threadIdx.x;
    #pragma unroll
    for (int i = 0; i < 4; ++i) {
        int idx = (tid + i * 256) * 4;
        *(float4*)&Wl[idx] = *(const float4*)&W[idx];
    }
    __syncthreads();

    const int k4 = (tid & 7) * 4;          // 8 lanes cover K=32
    const int rg = tid >> 3;               // 0..31 row groups
    const long row0 = (long)blockIdx.x * 128 + (long)rg * 4;
    const float* ip = inp + row0 * Ff;

    float acc[4][4];
    #pragma unroll
    for (int r = 0; r < 4; ++r)
        #pragma unroll
        for (int j = 0; j < 4; ++j) acc[r][j] = 0.f;

    for (int f = 0; f < Ff; f += 4) {
        float4 w0 = *(const float4*)&Wl[(f + 0) * Kk + k4];
        float4 w1 = *(const float4*)&Wl[(f + 1) * Kk + k4];
        float4 w2 = *(const float4*)&Wl[(f + 2) * Kk + k4];
        float4 w3 = *(const float4*)&Wl[(f + 3) * Kk + k4];
        #pragma unroll
        for (int r = 0; r < 4; ++r) {
            float4 x = *(const float4*)&ip[r * Ff + f];
            acc[r][0] += x.x * w0.x; acc[r][1] += x.x * w0.y;
            acc[r][2] += x.x * w0.z; acc[r][3] += x.x * w0.w;
            acc[r][0] += x.y * w1.x; acc[r][1] += x.y * w1.y;
            acc[r][2] += x.y * w1.z; acc[r][3] += x.y * w1.w;
            acc[r][0] += x.z * w2.x; acc[r][1] += x.z * w2.y;
            acc[r][2] += x.z * w2.z; acc[r][3] += x.z * w2.w;
            acc[r][0] += x.w * w3.x; acc[r][1] += x.w * w3.y;
            acc[r][2] += x.w * w3.z; acc[r][3] += x.w * w3.w;
        }
    }
    #pragma unroll
    for (int r = 0; r < 4; ++r) {
        *(float4*)&em[(row0 + r) * Kk + k4] =
            make_float4(acc[r][0], acc[r][1], acc[r][2], acc[r][3]);
    }
}

// ---------------------------------------------------------------------------
// Kernel 2: sequential CRF scan in linear space with carried log-scale.
//   alpha = c + log p ; step: q = p @ E ; p' = q * exp(em_t) ; rescale /8 steps
// One wave (64 threads) per batch. lane = (h, k): h = lane>>5 splits the
// j-reduction in half; p mirrored in both halves via 32-float LDS buffer.
// Single-wave block -> DS ops wave-ordered, no __syncthreads needed.
// Mask arrives as int32 (JAX bool -> int), NOT bytes.
// ---------------------------------------------------------------------------
__global__ __launch_bounds__(64) void scan_kernel(
    const float* __restrict__ em, const int* __restrict__ mask,
    const float* __restrict__ trans, float* __restrict__ out)
{
    const int b    = blockIdx.x;
    const int lane = threadIdx.x;
    const int h    = lane >> 5;
    const int k    = lane & 31;

    // E column fragment: e[i] = exp(trans[(h*16+i)][k])
    float e[16];
    #pragma unroll
    for (int i = 0; i < 16; ++i)
        e[i] = __expf(trans[(h * 16 + i) * Kk + k]);

    __shared__ __align__(16) float pl[Kk];

    const float* emb = em + (long)b * Tt * Kk;
    const int*   mb  = mask + (long)b * Tt;

    // prefetch chunk 0
    float embuf[8];
    #pragma unroll
    for (int i = 0; i < 8; ++i) embuf[i] = emb[i * Kk + k];
    int4 m0 = *(const int4*)(mb + 0);
    int4 m1 = *(const int4*)(mb + 4);
    int   mcur[8] = {m0.x, m0.y, m0.z, m0.w, m1.x, m1.y, m1.z, m1.w};

    // init from t = 0 (mask does not apply to alpha0)
    float a0 = embuf[0];
    float c  = __shfl(a0, 0);        // normalizer = alpha0[lane 0]
    float p  = __expf(a0 - c);
    pl[k] = p;                       // both halves write same value: benign

    for (int tc = 0; tc < Tt; tc += 8) {
        // prefetch next chunk's emissions + mask ints
        float nbuf[8];
        int   nmask[8];
        if (tc + 8 < Tt) {
            #pragma unroll
            for (int i = 0; i < 8; ++i)
                nbuf[i] = emb[(tc + 8 + i) * Kk + k];
            int4 a = *(const int4*)(mb + tc + 8);
            int4 bq = *(const int4*)(mb + tc + 12);
            nmask[0] = a.x;  nmask[1] = a.y;  nmask[2] = a.z;  nmask[3] = a.w;
            nmask[4] = bq.x; nmask[5] = bq.y; nmask[6] = bq.z; nmask[7] = bq.w;
        } else {
            #pragma unroll
            for (int i = 0; i < 8; ++i) { nbuf[i] = 0.f; nmask[i] = 0; }
        }

        #pragma unroll
        for (int i = 0; i < 8; ++i) {
            if (tc == 0 && i == 0) continue;   // t=0 already consumed as init
            // gather p (mirrored in both halves) and do half the j-sum
            float4 pv0 = *(const float4*)(pl + h * 16 + 0);
            float4 pv1 = *(const float4*)(pl + h * 16 + 4);
            float4 pv2 = *(const float4*)(pl + h * 16 + 8);
            float4 pv3 = *(const float4*)(pl + h * 16 + 12);
            float q0 = pv0.x * e[0]  + pv0.y * e[1]  + pv0.z * e[2]  + pv0.w * e[3];
            float q1 = pv1.x * e[4]  + pv1.y * e[5]  + pv1.z * e[6]  + pv1.w * e[7];
            float q2 = pv2.x * e[8]  + pv2.y * e[9]  + pv2.z * e[10] + pv2.w * e[11];
            float q3 = pv3.x * e[12] + pv3.y * e[13] + pv3.z * e[14] + pv3.w * e[15];
            float q = (q0 + q1) + (q2 + q3);
            q += __shfl_xor(q, 32);            // combine the two halves
            float r = q * __expf(embuf[i]);
            if (mcur[i] != 0) p = r;
            pl[k] = p;
        }

        // rescale every 8 steps: divide by lane-0's p, carry log into c
        float s = __shfl(p, 0);
        c += __logf(s);
        p *= (1.0f / s);
        pl[k] = p;

        #pragma unroll
        for (int i = 0; i < 8; ++i) { embuf[i] = nbuf[i]; mcur[i] = nmask[i]; }
    }

    // log_z = c + log(sum_k p_k); sum within one 32-lane half (mirrored)
    float sum = p;
    #pragma unroll
    for (int off = 16; off > 0; off >>= 1)
        sum += __shfl_xor(sum, off);
    if (lane == 0)
        atomicAdd(out, c + __logf(sum));
}

extern "C" void kernel_launch(void* const* d_in, const int* in_sizes, int n_in,
                              void* d_out, int out_size, void* d_ws, size_t ws_size,
                              hipStream_t stream)
{
    const float* inp   = (const float*)d_in[0];
    const int*   mask  = (const int*)d_in[1];
    const float* W     = (const float*)d_in[2];
    const float* trans = (const float*)d_in[3];
    float* out = (float*)d_out;
    float* em  = (float*)d_ws;     // 128*1024*32 fp32 = 16 MB scratch

    hipMemsetAsync(d_out, 0, sizeof(float), stream);
    emis_kernel<<<dim3(Bb * Tt / 128), dim3(256), 0, stream>>>(inp, W, em);
    scan_kernel<<<dim3(Bb), dim3(64), 0, stream>>>(em, mask, trans, out);
}

// Round 3
// 247.017 us; speedup vs baseline: 1.1122x; 1.1122x over previous
//
#include <hip/hip_runtime.h>

#define Bb 128
#define Tt 1024
#define Ff 128
#define Kk 32
#define SXS 130   // LDS row stride (floats): 130%32=2 -> 2-way bank alias (free), 8B aligned

// ---------------------------------------------------------------------------
// Kernel 1: emission[b,t,k] = sum_f input[b,t,f] * W[f,k]
// 2048 blocks x 128 threads; 64 rows/block staged in LDS (coalesced), W in LDS.
// Thread = (rg, k4): 4 rows x 4 k's from LDS. x reads float2 (2-way free),
// W reads float4 broadcast (conflict-free).
// ---------------------------------------------------------------------------
__global__ __launch_bounds__(128) void emis_kernel(
    const float* __restrict__ inp, const float* __restrict__ W,
    float* __restrict__ em)
{
    __shared__ float xs[64 * SXS];            // 33.3 KB
    __shared__ __align__(16) float Wl[Ff * Kk]; // 16 KB
    const int tid = threadIdx.x;

    // stage W: 4096 floats, 8 float4 per thread
    #pragma unroll
    for (int i = 0; i < 8; ++i) {
        int idx = (tid + i * 128) * 4;
        *(float4*)&Wl[idx] = *(const float4*)&W[idx];
    }
    // stage x: 64 rows x 128 f, coalesced float4 loads -> float2 LDS stores
    const float* gx = inp + (long)blockIdx.x * 64 * Ff;
    #pragma unroll
    for (int i = 0; i < 16; ++i) {
        int id = tid + i * 128;               // float4 index, 0..2047
        float4 v = ((const float4*)gx)[id];
        int row = id >> 5;                    // 32 float4 per row
        int col = (id & 31) * 4;
        float* dst = &xs[row * SXS + col];
        *(float2*)dst       = make_float2(v.x, v.y);
        *(float2*)(dst + 2) = make_float2(v.z, v.w);
    }
    __syncthreads();

    const int k4 = (tid & 7) * 4;             // 8 lanes cover K=32
    const int rg = tid >> 3;                  // 0..15 row groups
    const int r0 = rg * 4;
    const long grow0 = (long)blockIdx.x * 64 + r0;

    float acc[4][4];
    #pragma unroll
    for (int r = 0; r < 4; ++r)
        #pragma unroll
        for (int j = 0; j < 4; ++j) acc[r][j] = 0.f;

    #pragma unroll 2
    for (int f = 0; f < Ff; f += 4) {
        float4 w0 = *(const float4*)&Wl[(f + 0) * Kk + k4];
        float4 w1 = *(const float4*)&Wl[(f + 1) * Kk + k4];
        float4 w2 = *(const float4*)&Wl[(f + 2) * Kk + k4];
        float4 w3 = *(const float4*)&Wl[(f + 3) * Kk + k4];
        #pragma unroll
        for (int r = 0; r < 4; ++r) {
            const float* xr = &xs[(r0 + r) * SXS + f];
            float2 xa = *(const float2*)xr;
            float2 xb = *(const float2*)(xr + 2);
            acc[r][0] += xa.x * w0.x; acc[r][1] += xa.x * w0.y;
            acc[r][2] += xa.x * w0.z; acc[r][3] += xa.x * w0.w;
            acc[r][0] += xa.y * w1.x; acc[r][1] += xa.y * w1.y;
            acc[r][2] += xa.y * w1.z; acc[r][3] += xa.y * w1.w;
            acc[r][0] += xb.x * w2.x; acc[r][1] += xb.x * w2.y;
            acc[r][2] += xb.x * w2.z; acc[r][3] += xb.x * w2.w;
            acc[r][0] += xb.y * w3.x; acc[r][1] += xb.y * w3.y;
            acc[r][2] += xb.y * w3.z; acc[r][3] += xb.y * w3.w;
        }
    }
    #pragma unroll
    for (int r = 0; r < 4; ++r) {
        *(float4*)&em[(grow0 + r) * Kk + k4] =
            make_float4(acc[r][0], acc[r][1], acc[r][2], acc[r][3]);
    }
}

// ---------------------------------------------------------------------------
// Kernel 2: CRF scan, linear space + carried log-scale.
// One wave per batch; p_k in VGPR lane k (duplicated in upper half).
// Matvec via v_readlane (SGPR broadcast) -> no LDS round-trip on the
// critical path. exp(em) precomputed per 8-step chunk. Rescale by lane-0
// every 8 steps (identical numerics to the passing round-2 kernel).
// ---------------------------------------------------------------------------
__global__ __launch_bounds__(64) void scan_kernel(
    const float* __restrict__ em, const int* __restrict__ mask,
    const float* __restrict__ trans, float* __restrict__ out)
{
    const int b    = blockIdx.x;
    const int lane = threadIdx.x;
    const int k    = lane & 31;

    // full E column k per lane: e[j] = exp(trans[j][k]), j = 0..31
    float e[32];
    #pragma unroll
    for (int j = 0; j < 32; ++j)
        e[j] = __expf(trans[j * Kk + k]);

    const float* emb = em + (long)b * Tt * Kk;
    const int*   mb  = mask + (long)b * Tt;

    // chunk 0
    float raw[8]; int mc[8];
    #pragma unroll
    for (int i = 0; i < 8; ++i) raw[i] = emb[i * Kk + k];
    {
        int4 a = *(const int4*)(mb + 0);
        int4 c2 = *(const int4*)(mb + 4);
        mc[0]=a.x; mc[1]=a.y; mc[2]=a.z; mc[3]=a.w;
        mc[4]=c2.x; mc[5]=c2.y; mc[6]=c2.z; mc[7]=c2.w;
    }

    // init from t=0 (mask does not apply to alpha0)
    float a0 = raw[0];
    float c  = __int_as_float(__builtin_amdgcn_readlane(__float_as_int(a0), 0));
    float p  = __expf(a0 - c);

    float g[8];
    g[0] = 1.0f;
    #pragma unroll
    for (int i = 1; i < 8; ++i) g[i] = __expf(raw[i]);

    for (int tc = 0; tc < Tt; tc += 8) {
        // prefetch next chunk (latency hidden behind 8 steps)
        float nraw[8]; int nm[8];
        if (tc + 8 < Tt) {
            #pragma unroll
            for (int i = 0; i < 8; ++i)
                nraw[i] = emb[(tc + 8 + i) * Kk + k];
            int4 a = *(const int4*)(mb + tc + 8);
            int4 c2 = *(const int4*)(mb + tc + 12);
            nm[0]=a.x; nm[1]=a.y; nm[2]=a.z; nm[3]=a.w;
            nm[4]=c2.x; nm[5]=c2.y; nm[6]=c2.z; nm[7]=c2.w;
        } else {
            #pragma unroll
            for (int i = 0; i < 8; ++i) { nraw[i] = 0.f; nm[i] = 0; }
        }

        #pragma unroll
        for (int i = 0; i < 8; ++i) {
            if (tc == 0 && i == 0) continue;   // t=0 consumed as init
            const int pi = __float_as_int(p);
            float q0 = 0.f, q1 = 0.f, q2 = 0.f, q3 = 0.f;
            #pragma unroll
            for (int j = 0; j < 8; ++j) {
                q0 = fmaf(__int_as_float(__builtin_amdgcn_readlane(pi, j)),      e[j],      q0);
                q1 = fmaf(__int_as_float(__builtin_amdgcn_readlane(pi, j + 8)),  e[j + 8],  q1);
                q2 = fmaf(__int_as_float(__builtin_amdgcn_readlane(pi, j + 16)), e[j + 16], q2);
                q3 = fmaf(__int_as_float(__builtin_amdgcn_readlane(pi, j + 24)), e[j + 24], q3);
            }
            float q = (q0 + q1) + (q2 + q3);
            float r = q * g[i];
            p = mc[i] ? r : p;
        }

        // rescale every 8 steps by lane-0's p; carry log into c
        float s0 = __int_as_float(__builtin_amdgcn_readlane(__float_as_int(p), 0));
        c += __logf(s0);
        p *= (1.0f / s0);

        #pragma unroll
        for (int i = 0; i < 8; ++i) {
            raw[i] = nraw[i]; mc[i] = nm[i]; g[i] = __expf(nraw[i]);
        }
    }

    // log_z = c + log(sum_k p_k); lanes duplicate across halves, reduce 32
    float sum = p;
    #pragma unroll
    for (int off = 16; off > 0; off >>= 1)
        sum += __shfl_xor(sum, off);
    if (lane == 0)
        atomicAdd(out, c + __logf(sum));
}

extern "C" void kernel_launch(void* const* d_in, const int* in_sizes, int n_in,
                              void* d_out, int out_size, void* d_ws, size_t ws_size,
                              hipStream_t stream)
{
    const float* inp   = (const float*)d_in[0];
    const int*   mask  = (const int*)d_in[1];
    const float* W     = (const float*)d_in[2];
    const float* trans = (const float*)d_in[3];
    float* out = (float*)d_out;
    float* em  = (float*)d_ws;     // 128*1024*32 fp32 = 16 MB scratch

    hipMemsetAsync(d_out, 0, sizeof(float), stream);
    emis_kernel<<<dim3(Bb * Tt / 64), dim3(128), 0, stream>>>(inp, W, em);
    scan_kernel<<<dim3(Bb), dim3(64), 0, stream>>>(em, mask, trans, out);
}

// Round 4
// 151.621 us; speedup vs baseline: 1.8120x; 1.6292x over previous
//
#include <hip/hip_runtime.h>

#define Bb 128
#define Tt 1024
#define Ff 128
#define Kk 32
#define SXS 130
#define KS 36          // S LDS row stride (bf16 elems): 72 B, divisible by 8
#define KE 36          // g LDS row stride (floats): 144 B, divisible by 16
#define LOG32 3.4657359027997265f

typedef __attribute__((ext_vector_type(8))) short bf16x8;
typedef __attribute__((ext_vector_type(4))) float f32x4;

__device__ __forceinline__ float bf2f(unsigned u) {
    return __uint_as_float(u << 16);
}
__device__ __forceinline__ unsigned short f2bf(float f) {
    unsigned u = __float_as_uint(f);
    u = (u + 0x7fffu + ((u >> 16) & 1u)) >> 16;      // RNE
    return (unsigned short)u;
}
__device__ __forceinline__ unsigned bfpk(float a, float b) {
    unsigned ua = (__float_as_uint(a) + 0x8000u) >> 16;          // round-half-up
    unsigned ub = (__float_as_uint(b) + 0x8000u) & 0xffff0000u;
    return ua | ub;
}

// ---------------------------------------------------------------------------
// Kernel 1: emission[b,t,k] = sum_f input[b,t,f] * W[f,k]  -> bf16 out
// ---------------------------------------------------------------------------
__global__ __launch_bounds__(128) void emis_kernel(
    const float* __restrict__ inp, const float* __restrict__ W,
    unsigned short* __restrict__ em)
{
    __shared__ float xs[64 * SXS];
    __shared__ __align__(16) float Wl[Ff * Kk];
    const int tid = threadIdx.x;

    #pragma unroll
    for (int i = 0; i < 8; ++i) {
        int idx = (tid + i * 128) * 4;
        *(float4*)&Wl[idx] = *(const float4*)&W[idx];
    }
    const float* gx = inp + (long)blockIdx.x * 64 * Ff;
    #pragma unroll
    for (int i = 0; i < 16; ++i) {
        int id = tid + i * 128;
        float4 v = ((const float4*)gx)[id];
        int row = id >> 5;
        int col = (id & 31) * 4;
        float* dst = &xs[row * SXS + col];
        *(float2*)dst       = make_float2(v.x, v.y);
        *(float2*)(dst + 2) = make_float2(v.z, v.w);
    }
    __syncthreads();

    const int k4 = (tid & 7) * 4;
    const int rg = tid >> 3;
    const int r0 = rg * 4;
    const long grow0 = (long)blockIdx.x * 64 + r0;

    float acc[4][4];
    #pragma unroll
    for (int r = 0; r < 4; ++r)
        #pragma unroll
        for (int j = 0; j < 4; ++j) acc[r][j] = 0.f;

    #pragma unroll 2
    for (int f = 0; f < Ff; f += 4) {
        float4 w0 = *(const float4*)&Wl[(f + 0) * Kk + k4];
        float4 w1 = *(const float4*)&Wl[(f + 1) * Kk + k4];
        float4 w2 = *(const float4*)&Wl[(f + 2) * Kk + k4];
        float4 w3 = *(const float4*)&Wl[(f + 3) * Kk + k4];
        #pragma unroll
        for (int r = 0; r < 4; ++r) {
            const float* xr = &xs[(r0 + r) * SXS + f];
            float2 xa = *(const float2*)xr;
            float2 xb = *(const float2*)(xr + 2);
            acc[r][0] += xa.x * w0.x; acc[r][1] += xa.x * w0.y;
            acc[r][2] += xa.x * w0.z; acc[r][3] += xa.x * w0.w;
            acc[r][0] += xa.y * w1.x; acc[r][1] += xa.y * w1.y;
            acc[r][2] += xa.y * w1.z; acc[r][3] += xa.y * w1.w;
            acc[r][0] += xb.x * w2.x; acc[r][1] += xb.x * w2.y;
            acc[r][2] += xb.x * w2.z; acc[r][3] += xb.x * w2.w;
            acc[r][0] += xb.y * w3.x; acc[r][1] += xb.y * w3.y;
            acc[r][2] += xb.y * w3.z; acc[r][3] += xb.y * w3.w;
        }
    }
    #pragma unroll
    for (int r = 0; r < 4; ++r) {
        unsigned lo = bfpk(acc[r][0], acc[r][1]);
        unsigned hi = bfpk(acc[r][2], acc[r][3]);
        *(uint2*)&em[(grow0 + r) * Kk + k4] = make_uint2(lo, hi);
    }
}

// ---------------------------------------------------------------------------
// Kernel 2 (phase A): per (batch, chunk) compute S_c = Q_c^T (bf16 32x32),
// Q_c = product of step matrices M_t = exp(trans) * diag(exp(em_t)/32) over
// the chunk's unmasked steps.  Chain: S <- diag(g_t) * (E^T * S), S0 = I.
// One wave per block; E^T is the fixed MFMA A-operand; S lives in LDS
// column-major (Sl[col*KS+row]) so B-fragments are contiguous b64 reads.
// ---------------------------------------------------------------------------
__global__ __launch_bounds__(64) void chunk_kernel(
    const unsigned short* __restrict__ em, const int* __restrict__ mask,
    const float* __restrict__ trans, unsigned short* __restrict__ SQ)
{
    __shared__ __align__(16) float gl[32 * KE];
    __shared__ __align__(16) unsigned short Sl[32 * KS];
    const int lane = threadIdx.x & 63;
    const int q = lane >> 4, n = lane & 15;
    const int b = blockIdx.x >> 5, c = blockIdx.x & 31;
    const int t0 = c ? c * 32 : 1;
    const int L  = c ? 32 : 31;

    // Fixed A-operand: A_i[elem j] = E^T[i*16+n][q*8+j] = exp(trans[(q*8+j)*32 + i*16+n])
    bf16x8 A0, A1;
    #pragma unroll
    for (int j = 0; j < 8; ++j) {
        A0[j] = (short)f2bf(__expf(trans[(q * 8 + j) * Kk + n]));
        A1[j] = (short)f2bf(__expf(trans[(q * 8 + j) * Kk + 16 + n]));
    }

    // Stage g = exp(em - log32) for the chunk's rows
    const unsigned short* emp = em + ((long)b * Tt + t0) * Kk;
    #pragma unroll
    for (int it = 0; it < 4; ++it) {
        int f = it * 256 + lane * 4;
        if (f < L * 32) {
            uint2 r = *(const uint2*)(emp + f);
            float4 v;
            v.x = __expf(bf2f(r.x & 0xffffu) - LOG32);
            v.y = __expf(bf2f(r.x >> 16)     - LOG32);
            v.z = __expf(bf2f(r.y & 0xffffu) - LOG32);
            v.w = __expf(bf2f(r.y >> 16)     - LOG32);
            *(float4*)&gl[(f >> 5) * KE + (f & 31)] = v;
        }
    }

    // S = I (column-major bf16)
    for (int i = lane; i < (32 * KS) / 2; i += 64)
        ((unsigned*)Sl)[i] = 0u;
    if (lane < 32) Sl[lane * KS + lane] = 0x3f80;

    const int* mbp = mask + (long)b * Tt;
    const f32x4 zz = {0.f, 0.f, 0.f, 0.f};

    for (int s = 0; s < L; ++s) {
        if (mbp[t0 + s] == 0) continue;           // masked: S unchanged
        // B-frags: B_j[k][n] = S[k][j*16+n] = Sl[(j*16+n)*KS + k], k = q*8+jj
        uint2 xa = *(const uint2*)&Sl[ n       * KS + q * 8];
        uint2 xb = *(const uint2*)&Sl[ n       * KS + q * 8 + 4];
        uint2 ya = *(const uint2*)&Sl[(n + 16) * KS + q * 8];
        uint2 yb = *(const uint2*)&Sl[(n + 16) * KS + q * 8 + 4];
        uint4 u0 = make_uint4(xa.x, xa.y, xb.x, xb.y);
        uint4 u1 = make_uint4(ya.x, ya.y, yb.x, yb.y);
        bf16x8 B0 = __builtin_bit_cast(bf16x8, u0);
        bf16x8 B1 = __builtin_bit_cast(bf16x8, u1);
        f32x4 D00 = __builtin_amdgcn_mfma_f32_16x16x32_bf16(A0, B0, zz, 0, 0, 0);
        f32x4 D01 = __builtin_amdgcn_mfma_f32_16x16x32_bf16(A0, B1, zz, 0, 0, 0);
        f32x4 D10 = __builtin_amdgcn_mfma_f32_16x16x32_bf16(A1, B0, zz, 0, 0, 0);
        f32x4 D11 = __builtin_amdgcn_mfma_f32_16x16x32_bf16(A1, B1, zz, 0, 0, 0);
        // row scales: row = i*16 + q*4 + r
        float4 g0 = *(const float4*)&gl[s * KE + q * 4];
        float4 g1 = *(const float4*)&gl[s * KE + 16 + q * 4];
        // scale + pack + store S_new[row][col] at Sl[col*KS + row]
        *(uint2*)&Sl[ n       * KS      + q * 4] =
            make_uint2(bfpk(D00[0] * g0.x, D00[1] * g0.y), bfpk(D00[2] * g0.z, D00[3] * g0.w));
        *(uint2*)&Sl[(n + 16) * KS      + q * 4] =
            make_uint2(bfpk(D01[0] * g0.x, D01[1] * g0.y), bfpk(D01[2] * g0.z, D01[3] * g0.w));
        *(uint2*)&Sl[ n       * KS + 16 + q * 4] =
            make_uint2(bfpk(D10[0] * g1.x, D10[1] * g1.y), bfpk(D10[2] * g1.z, D10[3] * g1.w));
        *(uint2*)&Sl[(n + 16) * KS + 16 + q * 4] =
            make_uint2(bfpk(D11[0] * g1.x, D11[1] * g1.y), bfpk(D11[2] * g1.z, D11[3] * g1.w));
    }

    // Write S row-major to global: sq[k*32 + n] = S[k][n]  (transpose via LDS reads)
    unsigned short* sq = SQ + (long)(b * 32 + c) * 1024;
    #pragma unroll
    for (int it = 0; it < 2; ++it) {
        int f = it * 512 + lane * 8;
        int kk = f >> 5, n0 = f & 31;
        unsigned v[4];
        #pragma unroll
        for (int e = 0; e < 4; ++e) {
            unsigned lo = Sl[(n0 + 2 * e    ) * KS + kk];
            unsigned hi = Sl[(n0 + 2 * e + 1) * KS + kk];
            v[e] = lo | (hi << 16);
        }
        *(uint4*)(sq + f) = make_uint4(v[0], v[1], v[2], v[3]);
    }
}

// ---------------------------------------------------------------------------
// Kernel 3 (phase B): per batch, p^T <- p^T Q_c for c = 0..31 with per-step
// rescaling; p_new[k] = sum_j p_j S_c[k][j] (row k contiguous in SQ).
// ---------------------------------------------------------------------------
__global__ __launch_bounds__(64) void apply_kernel(
    const unsigned short* __restrict__ em, const int* __restrict__ mask,
    const unsigned short* __restrict__ SQ, float* __restrict__ out)
{
    const int b = blockIdx.x, lane = threadIdx.x & 63, k = lane & 31;
    const int* mbp = mask + (long)b * Tt;

    // count applied steps (t = 1..1023 with mask != 0)
    int cnt = 0;
    #pragma unroll
    for (int it = 0; it < 16; ++it) cnt += (mbp[it * 64 + lane] != 0) ? 1 : 0;
    #pragma unroll
    for (int off = 32; off; off >>= 1) cnt += __shfl_xor(cnt, off);
    cnt -= (mbp[0] != 0) ? 1 : 0;

    float a0 = bf2f(em[(long)b * Tt * Kk + k]);
    float c0 = __shfl(a0, 0);
    float p = __expf(a0 - c0);
    float csum = c0 + (float)cnt * LOG32;

    const unsigned short* sqb = SQ + (long)b * 32 * 1024;
    uint4 ra = *(const uint4*)(sqb + k * 32 +  0);
    uint4 rb = *(const uint4*)(sqb + k * 32 +  8);
    uint4 rc = *(const uint4*)(sqb + k * 32 + 16);
    uint4 rd = *(const uint4*)(sqb + k * 32 + 24);

    for (int c = 0; c < 32; ++c) {
        uint4 na, nb2, nc, nd;
        if (c + 1 < 32) {
            const unsigned short* s2 = sqb + (c + 1) * 1024 + k * 32;
            na  = *(const uint4*)(s2 +  0);
            nb2 = *(const uint4*)(s2 +  8);
            nc  = *(const uint4*)(s2 + 16);
            nd  = *(const uint4*)(s2 + 24);
        }
        const int pi = __float_as_int(p);
        float q0 = 0.f, q1 = 0.f, q2 = 0.f, q3 = 0.f;
        #define RL(j) __int_as_float(__builtin_amdgcn_readlane(pi, (j)))
        #define ACC2(word, j, acc) \
            acc = fmaf(bf2f((word) & 0xffffu), RL(j), acc); \
            acc = fmaf(bf2f((word) >> 16),     RL((j) + 1), acc);
        ACC2(ra.x,  0, q0) ACC2(ra.y,  2, q0) ACC2(ra.z,  4, q0) ACC2(ra.w,  6, q0)
        ACC2(rb.x,  8, q1) ACC2(rb.y, 10, q1) ACC2(rb.z, 12, q1) ACC2(rb.w, 14, q1)
        ACC2(rc.x, 16, q2) ACC2(rc.y, 18, q2) ACC2(rc.z, 20, q2) ACC2(rc.w, 22, q2)
        ACC2(rd.x, 24, q3) ACC2(rd.y, 26, q3) ACC2(rd.z, 28, q3) ACC2(rd.w, 30, q3)
        #undef ACC2
        #undef RL
        float qq = (q0 + q1) + (q2 + q3);
        float s0 = __int_as_float(__builtin_amdgcn_readlane(__float_as_int(qq), 0));
        csum += __logf(s0);
        p = qq * (1.0f / s0);
        ra = na; rb = nb2; rc = nc; rd = nd;
    }

    float sum = p;
    #pragma unroll
    for (int off = 16; off > 0; off >>= 1)
        sum += __shfl_xor(sum, off);
    if (lane == 0)
        atomicAdd(out, csum + __logf(sum));
}

extern "C" void kernel_launch(void* const* d_in, const int* in_sizes, int n_in,
                              void* d_out, int out_size, void* d_ws, size_t ws_size,
                              hipStream_t stream)
{
    const float* inp   = (const float*)d_in[0];
    const int*   mask  = (const int*)d_in[1];
    const float* W     = (const float*)d_in[2];
    const float* trans = (const float*)d_in[3];
    float* out = (float*)d_out;
    unsigned short* em = (unsigned short*)d_ws;                            // 8 MB bf16
    unsigned short* SQ = (unsigned short*)((char*)d_ws + (size_t)Bb * Tt * Kk * 2); // 8 MB

    hipMemsetAsync(d_out, 0, sizeof(float), stream);
    emis_kernel<<<dim3(Bb * Tt / 64), dim3(128), 0, stream>>>(inp, W, em);
    chunk_kernel<<<dim3(Bb * 32), dim3(64), 0, stream>>>(em, mask, trans, SQ);
    apply_kernel<<<dim3(Bb), dim3(64), 0, stream>>>(em, mask, SQ, out);
}

// Round 5
// 133.942 us; speedup vs baseline: 2.0512x; 1.1320x over previous
//
#include <hip/hip_runtime.h>

#define Bb 128
#define Tt 1024
#define Ff 128
#define Kk 32
#define KS 36          // S LDS row stride (bf16 elems): 72 B, divisible by 8
#define KE 36          // g LDS row stride (floats)
#define LOG32 3.4657359027997265f

typedef __attribute__((ext_vector_type(8))) short bf16x8;
typedef __attribute__((ext_vector_type(4))) float f32x4;

__device__ __forceinline__ float bf2f(unsigned u) {
    return __uint_as_float(u << 16);
}
__device__ __forceinline__ unsigned short f2bf(float f) {
    unsigned u = __float_as_uint(f);
    u = (u + 0x7fffu + ((u >> 16) & 1u)) >> 16;      // RNE
    return (unsigned short)u;
}
__device__ __forceinline__ unsigned bfpk(float a, float b) {
    unsigned ua = (__float_as_uint(a) + 0x8000u) >> 16;          // round-half-up
    unsigned ub = (__float_as_uint(b) + 0x8000u) & 0xffff0000u;
    return ua | ub;
}

// ---------------------------------------------------------------------------
// Kernel 1 (phase A, fused): per (batch, chunk):
//   1. emission tile em[t0..t0+31][0..31] = inp_rows @ W via 16 MFMAs
//      (bf16 in, fp32 accum); g = exp(em - log32) scattered to LDS.
//   2. S_c = Q_c^T chain: S <- diag(g_t) * (E^T * S) over unmasked steps.
//   3. write S row-major to SQ.
// One wave per block. E^T is the fixed MFMA A-operand.
// ---------------------------------------------------------------------------
__global__ __launch_bounds__(64, 4) void chunk_kernel(
    const float* __restrict__ inp, const int* __restrict__ mask,
    const float* __restrict__ W, const float* __restrict__ trans,
    unsigned short* __restrict__ SQ)
{
    __shared__ __align__(16) float gl[32 * KE];
    __shared__ __align__(16) unsigned short Sl[32 * KS];
    const int lane = threadIdx.x & 63;
    const int q = lane >> 4, n = lane & 15;
    const int b = blockIdx.x >> 5, c = blockIdx.x & 31;
    const int t0 = c ? c * 32 : 1;
    const int L  = c ? 32 : 31;

    // Fixed A-operand for the chain: A_i[j] = E^T[i*16+n][q*8+j]
    bf16x8 A0, A1;
    #pragma unroll
    for (int j = 0; j < 8; ++j) {
        A0[j] = (short)f2bf(__expf(trans[(q * 8 + j) * Kk + n]));
        A1[j] = (short)f2bf(__expf(trans[(q * 8 + j) * Kk + 16 + n]));
    }

    // ---- emission tile via MFMA: em[t0+m][k], m,k in [0,32) ----
    const f32x4 zz = {0.f, 0.f, 0.f, 0.f};
    f32x4 E00 = zz, E01 = zz, E10 = zz, E11 = zz;
    const float* xrow = inp + ((long)b * Tt + t0) * Ff;
    #pragma unroll
    for (int kt = 0; kt < 4; ++kt) {
        const int f0 = kt * 32 + q * 8;
        // A-frags: input rows t0 + mi*16 + n, cols f0..f0+7
        float4 al0 = *(const float4*)&xrow[ n        * Ff + f0];
        float4 al1 = *(const float4*)&xrow[ n        * Ff + f0 + 4];
        float4 ah0 = *(const float4*)&xrow[(n + 16)  * Ff + f0];
        float4 ah1 = *(const float4*)&xrow[(n + 16)  * Ff + f0 + 4];
        uint4 ua = make_uint4(bfpk(al0.x, al0.y), bfpk(al0.z, al0.w),
                              bfpk(al1.x, al1.y), bfpk(al1.z, al1.w));
        uint4 ub = make_uint4(bfpk(ah0.x, ah0.y), bfpk(ah0.z, ah0.w),
                              bfpk(ah1.x, ah1.y), bfpk(ah1.z, ah1.w));
        bf16x8 Alo = __builtin_bit_cast(bf16x8, ua);
        bf16x8 Ahi = __builtin_bit_cast(bf16x8, ub);
        // B-frags: W[f0+jj][n] and W[f0+jj][16+n]
        float wl[8], wh[8];
        #pragma unroll
        for (int jj = 0; jj < 8; ++jj) {
            wl[jj] = W[(f0 + jj) * Kk + n];
            wh[jj] = W[(f0 + jj) * Kk + 16 + n];
        }
        uint4 uc = make_uint4(bfpk(wl[0], wl[1]), bfpk(wl[2], wl[3]),
                              bfpk(wl[4], wl[5]), bfpk(wl[6], wl[7]));
        uint4 ud = make_uint4(bfpk(wh[0], wh[1]), bfpk(wh[2], wh[3]),
                              bfpk(wh[4], wh[5]), bfpk(wh[6], wh[7]));
        bf16x8 Blo = __builtin_bit_cast(bf16x8, uc);
        bf16x8 Bhi = __builtin_bit_cast(bf16x8, ud);
        E00 = __builtin_amdgcn_mfma_f32_16x16x32_bf16(Alo, Blo, E00, 0, 0, 0);
        E01 = __builtin_amdgcn_mfma_f32_16x16x32_bf16(Alo, Bhi, E01, 0, 0, 0);
        E10 = __builtin_amdgcn_mfma_f32_16x16x32_bf16(Ahi, Blo, E10, 0, 0, 0);
        E11 = __builtin_amdgcn_mfma_f32_16x16x32_bf16(Ahi, Bhi, E11, 0, 0, 0);
    }
    // scatter g = exp(em - log32): D row = t-offset (q*4+r [+16]), col = k (n [+16])
    #pragma unroll
    for (int r = 0; r < 4; ++r) {
        gl[( q * 4 + r)      * KE + n]      = __expf(E00[r] - LOG32);
        gl[( q * 4 + r)      * KE + 16 + n] = __expf(E01[r] - LOG32);
        gl[(16 + q * 4 + r)  * KE + n]      = __expf(E10[r] - LOG32);
        gl[(16 + q * 4 + r)  * KE + 16 + n] = __expf(E11[r] - LOG32);
    }

    // ---- S = I (column-major bf16) ----
    for (int i = lane; i < (32 * KS) / 2; i += 64)
        ((unsigned*)Sl)[i] = 0u;
    if (lane < 32) Sl[lane * KS + lane] = 0x3f80;

    const int* mbp = mask + (long)b * Tt;

    for (int s = 0; s < L; ++s) {
        if (mbp[t0 + s] == 0) continue;           // masked: S unchanged
        // B-frags: B_j[k][n] = S[k][j*16+n] = Sl[(j*16+n)*KS + k], k = q*8+jj
        uint2 xa = *(const uint2*)&Sl[ n       * KS + q * 8];
        uint2 xb = *(const uint2*)&Sl[ n       * KS + q * 8 + 4];
        uint2 ya = *(const uint2*)&Sl[(n + 16) * KS + q * 8];
        uint2 yb = *(const uint2*)&Sl[(n + 16) * KS + q * 8 + 4];
        uint4 u0 = make_uint4(xa.x, xa.y, xb.x, xb.y);
        uint4 u1 = make_uint4(ya.x, ya.y, yb.x, yb.y);
        bf16x8 B0 = __builtin_bit_cast(bf16x8, u0);
        bf16x8 B1 = __builtin_bit_cast(bf16x8, u1);
        f32x4 D00 = __builtin_amdgcn_mfma_f32_16x16x32_bf16(A0, B0, zz, 0, 0, 0);
        f32x4 D01 = __builtin_amdgcn_mfma_f32_16x16x32_bf16(A0, B1, zz, 0, 0, 0);
        f32x4 D10 = __builtin_amdgcn_mfma_f32_16x16x32_bf16(A1, B0, zz, 0, 0, 0);
        f32x4 D11 = __builtin_amdgcn_mfma_f32_16x16x32_bf16(A1, B1, zz, 0, 0, 0);
        float4 g0 = *(const float4*)&gl[s * KE + q * 4];
        float4 g1 = *(const float4*)&gl[s * KE + 16 + q * 4];
        *(uint2*)&Sl[ n       * KS      + q * 4] =
            make_uint2(bfpk(D00[0] * g0.x, D00[1] * g0.y), bfpk(D00[2] * g0.z, D00[3] * g0.w));
        *(uint2*)&Sl[(n + 16) * KS      + q * 4] =
            make_uint2(bfpk(D01[0] * g0.x, D01[1] * g0.y), bfpk(D01[2] * g0.z, D01[3] * g0.w));
        *(uint2*)&Sl[ n       * KS + 16 + q * 4] =
            make_uint2(bfpk(D10[0] * g1.x, D10[1] * g1.y), bfpk(D10[2] * g1.z, D10[3] * g1.w));
        *(uint2*)&Sl[(n + 16) * KS + 16 + q * 4] =
            make_uint2(bfpk(D11[0] * g1.x, D11[1] * g1.y), bfpk(D11[2] * g1.z, D11[3] * g1.w));
    }

    // Write S row-major to global: sq[k*32 + n] = S[k][n]
    unsigned short* sq = SQ + (long)(b * 32 + c) * 1024;
    #pragma unroll
    for (int it = 0; it < 2; ++it) {
        int f = it * 512 + lane * 8;
        int kk = f >> 5, n0 = f & 31;
        unsigned v[4];
        #pragma unroll
        for (int e = 0; e < 4; ++e) {
            unsigned lo = Sl[(n0 + 2 * e    ) * KS + kk];
            unsigned hi = Sl[(n0 + 2 * e + 1) * KS + kk];
            v[e] = lo | (hi << 16);
        }
        *(uint4*)(sq + f) = make_uint4(v[0], v[1], v[2], v[3]);
    }
}

// ---------------------------------------------------------------------------
// Kernel 2 (phase B): per batch, p^T <- p^T Q_c for c = 0..31 with per-chunk
// rescaling. alpha0 computed in fp32 directly from inp row 0 and W.
// ---------------------------------------------------------------------------
__global__ __launch_bounds__(64) void apply_kernel(
    const float* __restrict__ inp, const int* __restrict__ mask,
    const float* __restrict__ W, const unsigned short* __restrict__ SQ,
    float* __restrict__ out)
{
    const int b = blockIdx.x, lane = threadIdx.x & 63, k = lane & 31;
    const int* mbp = mask + (long)b * Tt;

    const unsigned short* sqb = SQ + (long)b * 32 * 1024;
    uint4 ra = *(const uint4*)(sqb + k * 32 +  0);
    uint4 rb = *(const uint4*)(sqb + k * 32 +  8);
    uint4 rc = *(const uint4*)(sqb + k * 32 + 16);
    uint4 rd = *(const uint4*)(sqb + k * 32 + 24);

    // count applied steps (t = 1..1023 with mask != 0)
    int cnt = 0;
    #pragma unroll
    for (int it = 0; it < 16; ++it) cnt += (mbp[it * 64 + lane] != 0) ? 1 : 0;
    #pragma unroll
    for (int off = 32; off; off >>= 1) cnt += __shfl_xor(cnt, off);
    cnt -= (mbp[0] != 0) ? 1 : 0;

    // alpha0[k] = dot(inp[b,0,:], W[:,k]) in fp32
    const float* x0 = inp + (long)b * Tt * Ff;
    float a0 = 0.f;
    #pragma unroll 4
    for (int f = 0; f < Ff; ++f)
        a0 = fmaf(x0[f], W[f * Kk + k], a0);

    float c0 = __int_as_float(__builtin_amdgcn_readlane(__float_as_int(a0), 0));
    float p = __expf(a0 - c0);
    float csum = c0 + (float)cnt * LOG32;

    for (int c = 0; c < 32; ++c) {
        uint4 na, nb2, nc, nd;
        if (c + 1 < 32) {
            const unsigned short* s2 = sqb + (c + 1) * 1024 + k * 32;
            na  = *(const uint4*)(s2 +  0);
            nb2 = *(const uint4*)(s2 +  8);
            nc  = *(const uint4*)(s2 + 16);
            nd  = *(const uint4*)(s2 + 24);
        }
        const int pi = __float_as_int(p);
        float q0 = 0.f, q1 = 0.f, q2 = 0.f, q3 = 0.f;
        #define RL(j) __int_as_float(__builtin_amdgcn_readlane(pi, (j)))
        #define ACC2(word, j, acc) \
            acc = fmaf(bf2f((word) & 0xffffu), RL(j), acc); \
            acc = fmaf(bf2f((word) >> 16),     RL((j) + 1), acc);
        ACC2(ra.x,  0, q0) ACC2(ra.y,  2, q0) ACC2(ra.z,  4, q0) ACC2(ra.w,  6, q0)
        ACC2(rb.x,  8, q1) ACC2(rb.y, 10, q1) ACC2(rb.z, 12, q1) ACC2(rb.w, 14, q1)
        ACC2(rc.x, 16, q2) ACC2(rc.y, 18, q2) ACC2(rc.z, 20, q2) ACC2(rc.w, 22, q2)
        ACC2(rd.x, 24, q3) ACC2(rd.y, 26, q3) ACC2(rd.z, 28, q3) ACC2(rd.w, 30, q3)
        #undef ACC2
        #undef RL
        float qq = (q0 + q1) + (q2 + q3);
        float s0 = __int_as_float(__builtin_amdgcn_readlane(__float_as_int(qq), 0));
        csum += __logf(s0);
        p = qq * (1.0f / s0);
        ra = na; rb = nb2; rc = nc; rd = nd;
    }

    float sum = p;
    #pragma unroll
    for (int off = 16; off > 0; off >>= 1)
        sum += __shfl_xor(sum, off);
    if (lane == 0)
        atomicAdd(out, csum + __logf(sum));
}

extern "C" void kernel_launch(void* const* d_in, const int* in_sizes, int n_in,
                              void* d_out, int out_size, void* d_ws, size_t ws_size,
                              hipStream_t stream)
{
    const float* inp   = (const float*)d_in[0];
    const int*   mask  = (const int*)d_in[1];
    const float* W     = (const float*)d_in[2];
    const float* trans = (const float*)d_in[3];
    float* out = (float*)d_out;
    unsigned short* SQ = (unsigned short*)d_ws;   // 128*32 chunk matrices * 2 KB = 8 MB

    hipMemsetAsync(d_out, 0, sizeof(float), stream);
    chunk_kernel<<<dim3(Bb * 32), dim3(64), 0, stream>>>(inp, mask, W, trans, SQ);
    apply_kernel<<<dim3(Bb), dim3(64), 0, stream>>>(inp, mask, W, SQ, out);
}

// Round 6
// 132.020 us; speedup vs baseline: 2.0810x; 1.0146x over previous
//
#include <hip/hip_runtime.h>

#define Bb 128
#define Tt 1024
#define Ff 128
#define Kk 32
#define KS 36          // S LDS row stride (bf16 elems): 72 B, divisible by 8
#define KE 36          // g LDS row stride (floats)
#define LOG32 3.4657359027997265f

typedef __attribute__((ext_vector_type(8))) short bf16x8;
typedef __attribute__((ext_vector_type(4))) float f32x4;

__device__ __forceinline__ float bf2f(unsigned u) {
    return __uint_as_float(u << 16);
}
__device__ __forceinline__ unsigned short f2bf(float f) {
    unsigned u = __float_as_uint(f);
    u = (u + 0x7fffu + ((u >> 16) & 1u)) >> 16;      // RNE
    return (unsigned short)u;
}
__device__ __forceinline__ unsigned bfpk(float a, float b) {
    unsigned ua = (__float_as_uint(a) + 0x8000u) >> 16;          // round-half-up
    unsigned ub = (__float_as_uint(b) + 0x8000u) & 0xffff0000u;
    return ua | ub;
}

// ---------------------------------------------------------------------------
// Kernel 1 (phase A, fused): per (batch, chunk):
//   1. emission tile em[t0..t0+31][0..31] = inp_rows @ W via 16 MFMAs
//      (bf16 in, fp32 accum); g = exp(em - log32) scattered to LDS.
//   2. S_c = Q_c^T chain: S <- diag(g_t) * (E^T * S) over unmasked steps.
//      Mask preloaded into a wave-uniform bitmask (no per-step scalar loads).
//   3. write S row-major to SQ.
// One wave per block. E^T is the fixed MFMA A-operand.
// ---------------------------------------------------------------------------
__global__ __launch_bounds__(64, 4) void chunk_kernel(
    const float* __restrict__ inp, const int* __restrict__ mask,
    const float* __restrict__ W, const float* __restrict__ trans,
    unsigned short* __restrict__ SQ)
{
    __shared__ __align__(16) float gl[32 * KE];
    __shared__ __align__(16) unsigned short Sl[32 * KS];
    const int lane = threadIdx.x & 63;
    const int q = lane >> 4, n = lane & 15;
    const int b = blockIdx.x >> 5, c = blockIdx.x & 31;
    const int t0 = c ? c * 32 : 1;
    const int L  = c ? 32 : 31;

    // Preload this chunk's mask into a wave-uniform bitmask: bit s = mask[t0+s]
    const int* mbp = mask + (long)b * Tt;
    int mybit = (lane < L) ? (mbp[t0 + lane] != 0) : 0;
    const unsigned mbits = (unsigned)__ballot(mybit);

    // Fixed A-operand for the chain: A_i[j] = E^T[i*16+n][q*8+j]
    bf16x8 A0, A1;
    #pragma unroll
    for (int j = 0; j < 8; ++j) {
        A0[j] = (short)f2bf(__expf(trans[(q * 8 + j) * Kk + n]));
        A1[j] = (short)f2bf(__expf(trans[(q * 8 + j) * Kk + 16 + n]));
    }

    // ---- emission tile via MFMA: em[t0+m][k], m,k in [0,32) ----
    const f32x4 zz = {0.f, 0.f, 0.f, 0.f};
    f32x4 E00 = zz, E01 = zz, E10 = zz, E11 = zz;
    const float* xrow = inp + ((long)b * Tt + t0) * Ff;
    #pragma unroll
    for (int kt = 0; kt < 4; ++kt) {
        const int f0 = kt * 32 + q * 8;
        float4 al0 = *(const float4*)&xrow[ n        * Ff + f0];
        float4 al1 = *(const float4*)&xrow[ n        * Ff + f0 + 4];
        float4 ah0 = *(const float4*)&xrow[(n + 16)  * Ff + f0];
        float4 ah1 = *(const float4*)&xrow[(n + 16)  * Ff + f0 + 4];
        uint4 ua = make_uint4(bfpk(al0.x, al0.y), bfpk(al0.z, al0.w),
                              bfpk(al1.x, al1.y), bfpk(al1.z, al1.w));
        uint4 ub = make_uint4(bfpk(ah0.x, ah0.y), bfpk(ah0.z, ah0.w),
                              bfpk(ah1.x, ah1.y), bfpk(ah1.z, ah1.w));
        bf16x8 Alo = __builtin_bit_cast(bf16x8, ua);
        bf16x8 Ahi = __builtin_bit_cast(bf16x8, ub);
        float wl[8], wh[8];
        #pragma unroll
        for (int jj = 0; jj < 8; ++jj) {
            wl[jj] = W[(f0 + jj) * Kk + n];
            wh[jj] = W[(f0 + jj) * Kk + 16 + n];
        }
        uint4 uc = make_uint4(bfpk(wl[0], wl[1]), bfpk(wl[2], wl[3]),
                              bfpk(wl[4], wl[5]), bfpk(wl[6], wl[7]));
        uint4 ud = make_uint4(bfpk(wh[0], wh[1]), bfpk(wh[2], wh[3]),
                              bfpk(wh[4], wh[5]), bfpk(wh[6], wh[7]));
        bf16x8 Blo = __builtin_bit_cast(bf16x8, uc);
        bf16x8 Bhi = __builtin_bit_cast(bf16x8, ud);
        E00 = __builtin_amdgcn_mfma_f32_16x16x32_bf16(Alo, Blo, E00, 0, 0, 0);
        E01 = __builtin_amdgcn_mfma_f32_16x16x32_bf16(Alo, Bhi, E01, 0, 0, 0);
        E10 = __builtin_amdgcn_mfma_f32_16x16x32_bf16(Ahi, Blo, E10, 0, 0, 0);
        E11 = __builtin_amdgcn_mfma_f32_16x16x32_bf16(Ahi, Bhi, E11, 0, 0, 0);
    }
    // scatter g = exp(em - log32): D row = t-offset (q*4+r [+16]), col = k (n [+16])
    #pragma unroll
    for (int r = 0; r < 4; ++r) {
        gl[( q * 4 + r)      * KE + n]      = __expf(E00[r] - LOG32);
        gl[( q * 4 + r)      * KE + 16 + n] = __expf(E01[r] - LOG32);
        gl[(16 + q * 4 + r)  * KE + n]      = __expf(E10[r] - LOG32);
        gl[(16 + q * 4 + r)  * KE + 16 + n] = __expf(E11[r] - LOG32);
    }

    // ---- S = I (column-major bf16) ----
    for (int i = lane; i < (32 * KS) / 2; i += 64)
        ((unsigned*)Sl)[i] = 0u;
    if (lane < 32) Sl[lane * KS + lane] = 0x3f80;

    for (int s = 0; s < L; ++s) {
        if (!((mbits >> s) & 1u)) continue;       // masked: S unchanged (SALU only)
        // B-frags: B_j[k][n] = S[k][j*16+n] = Sl[(j*16+n)*KS + k], k = q*8+jj
        uint2 xa = *(const uint2*)&Sl[ n       * KS + q * 8];
        uint2 xb = *(const uint2*)&Sl[ n       * KS + q * 8 + 4];
        uint2 ya = *(const uint2*)&Sl[(n + 16) * KS + q * 8];
        uint2 yb = *(const uint2*)&Sl[(n + 16) * KS + q * 8 + 4];
        uint4 u0 = make_uint4(xa.x, xa.y, xb.x, xb.y);
        uint4 u1 = make_uint4(ya.x, ya.y, yb.x, yb.y);
        bf16x8 B0 = __builtin_bit_cast(bf16x8, u0);
        bf16x8 B1 = __builtin_bit_cast(bf16x8, u1);
        f32x4 D00 = __builtin_amdgcn_mfma_f32_16x16x32_bf16(A0, B0, zz, 0, 0, 0);
        f32x4 D01 = __builtin_amdgcn_mfma_f32_16x16x32_bf16(A0, B1, zz, 0, 0, 0);
        f32x4 D10 = __builtin_amdgcn_mfma_f32_16x16x32_bf16(A1, B0, zz, 0, 0, 0);
        f32x4 D11 = __builtin_amdgcn_mfma_f32_16x16x32_bf16(A1, B1, zz, 0, 0, 0);
        float4 g0 = *(const float4*)&gl[s * KE + q * 4];
        float4 g1 = *(const float4*)&gl[s * KE + 16 + q * 4];
        *(uint2*)&Sl[ n       * KS      + q * 4] =
            make_uint2(bfpk(D00[0] * g0.x, D00[1] * g0.y), bfpk(D00[2] * g0.z, D00[3] * g0.w));
        *(uint2*)&Sl[(n + 16) * KS      + q * 4] =
            make_uint2(bfpk(D01[0] * g0.x, D01[1] * g0.y), bfpk(D01[2] * g0.z, D01[3] * g0.w));
        *(uint2*)&Sl[ n       * KS + 16 + q * 4] =
            make_uint2(bfpk(D10[0] * g1.x, D10[1] * g1.y), bfpk(D10[2] * g1.z, D10[3] * g1.w));
        *(uint2*)&Sl[(n + 16) * KS + 16 + q * 4] =
            make_uint2(bfpk(D11[0] * g1.x, D11[1] * g1.y), bfpk(D11[2] * g1.z, D11[3] * g1.w));
    }

    // Write S row-major to global: sq[k*32 + n] = S[k][n]
    unsigned short* sq = SQ + (long)(b * 32 + c) * 1024;
    #pragma unroll
    for (int it = 0; it < 2; ++it) {
        int f = it * 512 + lane * 8;
        int kk = f >> 5, n0 = f & 31;
        unsigned v[4];
        #pragma unroll
        for (int e = 0; e < 4; ++e) {
            unsigned lo = Sl[(n0 + 2 * e    ) * KS + kk];
            unsigned hi = Sl[(n0 + 2 * e + 1) * KS + kk];
            v[e] = lo | (hi << 16);
        }
        *(uint4*)(sq + f) = make_uint4(v[0], v[1], v[2], v[3]);
    }
}

// ---------------------------------------------------------------------------
// Kernel 2 (phase B): per batch, p^T <- p^T Q_c for c = 0..31.
// Two-deep prefetch of chunk matrices; normalization only at mid-point
// (unnormalized p drifts ~e^{+-40} max — safe in fp32).
// ---------------------------------------------------------------------------
__global__ __launch_bounds__(64) void apply_kernel(
    const float* __restrict__ inp, const int* __restrict__ mask,
    const float* __restrict__ W, const unsigned short* __restrict__ SQ,
    float* __restrict__ out)
{
    const int b = blockIdx.x, lane = threadIdx.x & 63, k = lane & 31;
    const int* mbp = mask + (long)b * Tt;

    const unsigned short* sqb = SQ + (long)b * 32 * 1024;
    uint4 cur[4], nxt[4];
    #pragma unroll
    for (int e = 0; e < 4; ++e) cur[e] = *(const uint4*)(sqb + k * 32 + 8 * e);
    #pragma unroll
    for (int e = 0; e < 4; ++e) nxt[e] = *(const uint4*)(sqb + 1024 + k * 32 + 8 * e);

    // count applied steps (t = 1..1023 with mask != 0)
    int cnt = 0;
    #pragma unroll
    for (int it = 0; it < 16; ++it) cnt += (mbp[it * 64 + lane] != 0) ? 1 : 0;
    #pragma unroll
    for (int off = 32; off; off >>= 1) cnt += __shfl_xor(cnt, off);
    cnt -= (mbp[0] != 0) ? 1 : 0;

    // alpha0[k] = dot(inp[b,0,:], W[:,k]) in fp32
    const float* x0 = inp + (long)b * Tt * Ff;
    float a0 = 0.f;
    #pragma unroll 4
    for (int f = 0; f < Ff; ++f)
        a0 = fmaf(x0[f], W[f * Kk + k], a0);

    float c0 = __int_as_float(__builtin_amdgcn_readlane(__float_as_int(a0), 0));
    float p = __expf(a0 - c0);
    float csum = c0 + (float)cnt * LOG32;

    for (int c = 0; c < 32; ++c) {
        uint4 pf[4];
        if (c + 2 < 32) {
            const unsigned short* s2 = sqb + (c + 2) * 1024 + k * 32;
            #pragma unroll
            for (int e = 0; e < 4; ++e) pf[e] = *(const uint4*)(s2 + 8 * e);
        }
        const int pi = __float_as_int(p);
        float q0 = 0.f, q1 = 0.f, q2 = 0.f, q3 = 0.f;
        #define RL(j) __int_as_float(__builtin_amdgcn_readlane(pi, (j)))
        #define ACC2(word, j, acc) \
            acc = fmaf(bf2f((word) & 0xffffu), RL(j), acc); \
            acc = fmaf(bf2f((word) >> 16),     RL((j) + 1), acc);
        ACC2(cur[0].x,  0, q0) ACC2(cur[0].y,  2, q0) ACC2(cur[0].z,  4, q0) ACC2(cur[0].w,  6, q0)
        ACC2(cur[1].x,  8, q1) ACC2(cur[1].y, 10, q1) ACC2(cur[1].z, 12, q1) ACC2(cur[1].w, 14, q1)
        ACC2(cur[2].x, 16, q2) ACC2(cur[2].y, 18, q2) ACC2(cur[2].z, 20, q2) ACC2(cur[2].w, 22, q2)
        ACC2(cur[3].x, 24, q3) ACC2(cur[3].y, 26, q3) ACC2(cur[3].z, 28, q3) ACC2(cur[3].w, 30, q3)
        #undef ACC2
        #undef RL
        float qq = (q0 + q1) + (q2 + q3);
        if (c == 15) {   // single mid-point rescale keeps p well inside fp32
            float s0 = __int_as_float(__builtin_amdgcn_readlane(__float_as_int(qq), 0));
            csum += __logf(s0);
            qq *= (1.0f / s0);
        }
        p = qq;
        #pragma unroll
        for (int e = 0; e < 4; ++e) { cur[e] = nxt[e]; nxt[e] = pf[e]; }
    }

    float sum = p;
    #pragma unroll
    for (int off = 16; off > 0; off >>= 1)
        sum += __shfl_xor(sum, off);
    if (lane == 0)
        atomicAdd(out, csum + __logf(sum));
}

extern "C" void kernel_launch(void* const* d_in, const int* in_sizes, int n_in,
                              void* d_out, int out_size, void* d_ws, size_t ws_size,
                              hipStream_t stream)
{
    const float* inp   = (const float*)d_in[0];
    const int*   mask  = (const int*)d_in[1];
    const float* W     = (const float*)d_in[2];
    const float* trans = (const float*)d_in[3];
    float* out = (float*)d_out;
    unsigned short* SQ = (unsigned short*)d_ws;   // 128*32 chunk matrices * 2 KB = 8 MB

    hipMemsetAsync(d_out, 0, sizeof(float), stream);
    chunk_kernel<<<dim3(Bb * 32), dim3(64), 0, stream>>>(inp, mask, W, trans, SQ);
    apply_kernel<<<dim3(Bb), dim3(64), 0, stream>>>(inp, mask, W, SQ, out);
}